// Round 3
// baseline (224.037 us; speedup 1.0000x reference)
//
#include <hip/hip_runtime.h>

#define NCELLS (8192 * 7 * 7)      // 401408 cells of 30 floats each
#define BLOCK 128                  // 2 waves
#define CPB 128                    // cells per block
#define NBLOCKS (NCELLS / CPB)     // 3136 exactly
#define POISON 0xAAAAAAAAu         // harness poisons d_ws with 0xAA before every launch
// last-block test via modulo: robust even if re-poison is skipped between iterations
#define LAST_MOD ((POISON % (unsigned)NBLOCKS + (unsigned)NBLOCKS - 1u) % (unsigned)NBLOCKS)
// LDS: 128 cells * 30 floats * 4 B * 2 arrays = 30720 B -> 5 blocks/CU = 10 waves/CU

__device__ __forceinline__ float sq(float x) { return x * x; }

__device__ __forceinline__ float iou_fn(const float* t, const float* p, float fi, float fj) {
    const float STEP = 1.0f / 7.0f;
    float w1 = t[2], h1 = t[3];
    float x1 = (t[0] + fj) * STEP, y1 = (t[1] + fi) * STEP;
    float a1 = fmaxf(x1 - w1 * 0.5f, 0.0f);
    float b1 = fmaxf(y1 - h1 * 0.5f, 0.0f);
    float w2 = p[2], h2 = p[3];
    float x2 = (p[0] + fj) * STEP, y2 = (p[1] + fi) * STEP;
    float a2 = fmaxf(x2 - w2 * 0.5f, 0.0f);
    float b2 = fmaxf(y2 - h2 * 0.5f, 0.0f);
    float iw = w1 + w2 - (fmaxf(a1 + w1, a2 + w2) - fminf(a1, a2));
    float ih = h1 + h2 - (fmaxf(b1 + h1, b2 + h2) - fminf(b1, b2));
    bool valid = (iw > 0.0f) && (ih > 0.0f);
    float inter = valid ? iw * ih : 0.0f;
    float uni = w1 * h1 + w2 * h2 - inter;
    return valid ? inter / uni : 0.0f;
}

// Single kernel. Staging via global_load_lds (linear dest = the one supported
// pattern; no VGPR round-trip). Per-block partial -> d_ws slot; decoupled
// last-block fold (store -> threadfence -> atomicAdd; rocPRIM-style) removes
// the 2nd dispatch and its launch gap.
__global__ __launch_bounds__(BLOCK) void yolo_fused_kernel(
        const float* __restrict__ pred, const float* __restrict__ target,
        float4* __restrict__ partials, unsigned* __restrict__ cnt,
        float* __restrict__ out) {
    __shared__ float s[2 * CPB * 30];          // [0,3840) pred chunk, [3840,7680) target
    const int tid = threadIdx.x;
    const int bid = blockIdx.x;

    // ---- stage: 1920 x 16B (960 pred + 960 target), 15 rounds exactly ----
    const size_t blockBase = (size_t)bid * (CPB * 30);          // floats, 16B-aligned
    const float4* gp = (const float4*)(pred + blockBase);
    const float4* gt = (const float4*)(target + blockBase);
    float4* ls = (float4*)s;
#pragma unroll
    for (int r = 0; r < 15; ++r) {
        int i = r * BLOCK + tid;               // 0..1919; 960 is a wave boundary ->
        const float4* base = (i < 960) ? gp : (gt - 960);   // no intra-wave divergence
        __builtin_amdgcn_global_load_lds(
            (const __attribute__((address_space(1))) void*)&base[i],
            (__attribute__((address_space(3))) void*)&ls[i], 16, 0, 0);
    }
    __syncthreads();                           // compiler drains vmcnt(0) before barrier

    // ---- compute: one cell per thread, operands from LDS (identical to R2) ----
    int c = bid * CPB + tid;
    unsigned cell = (unsigned)c % 49u;
    float fi = (float)(cell / 7u);
    float fj = (float)(cell % 7u);

    const float* pl = s + tid * 30;            // stride-30: 4-way bank alias, negligible
    const float* tl = s + CPB * 30 + tid * 30;

    bool obj = tl[4] > 0.0f;                   // target[...,4] is exactly 1.0 or 0.0

    float iou1 = iou_fn(tl, pl, fi, fj);
    float iou2 = iou_fn(tl, pl + 5, fi, fj);
    bool choose1 = iou1 > iou2;
    float m1 = (obj && choose1 && (iou1 != 0.0f)) ? 1.0f : 0.0f;
    float m2 = (obj && !choose1 && (iou2 != 0.0f)) ? 1.0f : 0.0f;

    float obj_loss = m1 * sq(iou1 - pl[4]) + m2 * sq(iou2 - pl[9]);

    float xy = m1 * (sq(tl[0] - pl[0]) + sq(tl[1] - pl[1]))
             + m2 * (sq(tl[5] - pl[5]) + sq(tl[6] - pl[6]));

    float wh = m1 * (sq(sqrtf(tl[2]) - sqrtf(pl[2])) + sq(sqrtf(tl[3]) - sqrtf(pl[3])))
             + m2 * (sq(sqrtf(tl[7]) - sqrtf(pl[7])) + sq(sqrtf(tl[8]) - sqrtf(pl[8])));

    float noobj = 0.0f;
#pragma unroll
    for (int k = 0; k < 6; ++k) {
        int ci = 4 + 5 * k;                    // 4, 9, 14, 19, 24, 29
        noobj += sq(tl[ci] - pl[ci]);
    }
    if (obj) noobj = 0.0f;

    float clsum = 0.0f;
#pragma unroll
    for (int k = 10; k < 30; ++k) clsum += sq(pl[k] - tl[k]);
    if (!obj) clsum = 0.0f;

    float conf = obj_loss + 0.5f * noobj;
    float reg  = xy + wh;
    float cls  = clsum;

#pragma unroll
    for (int off = 32; off > 0; off >>= 1) {
        conf += __shfl_down(conf, off, 64);
        reg  += __shfl_down(reg,  off, 64);
        cls  += __shfl_down(cls,  off, 64);
    }

    __shared__ float sr[3][2];
    __shared__ int amLast;
    int lane = tid & 63;
    int wave = tid >> 6;
    if (lane == 0) { sr[0][wave] = conf; sr[1][wave] = reg; sr[2][wave] = cls; }
    __syncthreads();

    if (tid == 0) {
        const float invB = 1.0f / 8192.0f;     // sum-then-scale, matches ref order
        partials[bid] = make_float4(
            (sr[0][0] + sr[0][1]) * invB,
            (sr[1][0] + sr[1][1]) * (5.0f * invB),
            (sr[2][0] + sr[2][1]) * invB,
            0.0f);
        __threadfence();                       // release: partial visible device-wide
        unsigned old = atomicAdd(cnt, 1u);     // device-scope RMW at coherent point
        amLast = ((old % (unsigned)NBLOCKS) == LAST_MOD) ? 1 : 0;
    }
    __syncthreads();                           // broadcast amLast (also orders sr reuse)

    if (amLast) {                              // uniform across block
        __threadfence();                       // acquire: see all blocks' partials
        float a = 0.0f, b = 0.0f, d = 0.0f;
        for (int i = tid; i < NBLOCKS; i += BLOCK) {
            float4 v = partials[i];
            a += v.x; b += v.y; d += v.z;
        }
#pragma unroll
        for (int off = 32; off > 0; off >>= 1) {
            a += __shfl_down(a, off, 64);
            b += __shfl_down(b, off, 64);
            d += __shfl_down(d, off, 64);
        }
        if (lane == 0) { sr[0][wave] = a; sr[1][wave] = b; sr[2][wave] = d; }
        __syncthreads();
        if (tid == 0) {
            out[0] = sr[0][0] + sr[0][1];
            out[1] = sr[1][0] + sr[1][1];
            out[2] = sr[2][0] + sr[2][1];
        }
    }
}

extern "C" void kernel_launch(void* const* d_in, const int* in_sizes, int n_in,
                              void* d_out, int out_size, void* d_ws, size_t ws_size,
                              hipStream_t stream) {
    const float* pred   = (const float*)d_in[0];
    const float* target = (const float*)d_in[1];
    float* out = (float*)d_out;
    float4* partials = (float4*)d_ws;          // 3136 * 16 B; every slot written before read
    unsigned* cnt = (unsigned*)(partials + NBLOCKS);   // poisoned 0xAAAAAAAA, handled via mod

    yolo_fused_kernel<<<NBLOCKS, BLOCK, 0, stream>>>(pred, target, partials, cnt, out);
}

// Round 4
// 112.054 us; speedup vs baseline: 1.9994x; 1.9994x over previous
//
#include <hip/hip_runtime.h>

#define NCELLS (8192 * 7 * 7)      // 401408 cells of 30 floats each
#define BLOCK 128                  // 2 waves
#define CPB 128                    // cells per block
#define NBLOCKS (NCELLS / CPB)     // 3136 exactly
// Two-phase LDS: one 15360 B buffer reused (target then pred)
// -> 10 blocks/CU = 20 waves/CU (vs R2's 5 blocks / 10 waves at 31 KB).
// __launch_bounds__(128,5): 5 waves/SIMD -> VGPR cap 102 (est. use ~98).

__device__ __forceinline__ float sq(float x) { return x * x; }

__device__ __forceinline__ float iou_fn(const float* t, const float* p, float fi, float fj) {
    const float STEP = 1.0f / 7.0f;
    float w1 = t[2], h1 = t[3];
    float x1 = (t[0] + fj) * STEP, y1 = (t[1] + fi) * STEP;
    float a1 = fmaxf(x1 - w1 * 0.5f, 0.0f);
    float b1 = fmaxf(y1 - h1 * 0.5f, 0.0f);
    float w2 = p[2], h2 = p[3];
    float x2 = (p[0] + fj) * STEP, y2 = (p[1] + fi) * STEP;
    float a2 = fmaxf(x2 - w2 * 0.5f, 0.0f);
    float b2 = fmaxf(y2 - h2 * 0.5f, 0.0f);
    float iw = w1 + w2 - (fmaxf(a1 + w1, a2 + w2) - fminf(a1, a2));
    float ih = h1 + h2 - (fmaxf(b1 + h1, b2 + h2) - fminf(b1, b2));
    bool valid = (iw > 0.0f) && (ih > 0.0f);
    float inter = valid ? iw * ih : 0.0f;
    float uni = w1 * h1 + w2 * h2 - inter;
    return valid ? inter / uni : 0.0f;
}

// Pass 1 (R2 structure, NO fences/atomics — R3's per-block __threadfence tail
// serialized 3136 cross-XCD L2 writebacks and cost 7x; kernel-boundary
// visibility is the cheap path). Two-phase staging halves LDS.
__global__ __launch_bounds__(BLOCK, 5) void yolo_part_kernel(
        const float* __restrict__ pred, const float* __restrict__ target,
        float4* __restrict__ partials) {
    __shared__ float s[CPB * 30];              // 15360 B, reused: target then pred
    const int tid = threadIdx.x;
    const size_t blockBase = (size_t)blockIdx.x * (CPB * 30);   // floats, 16B-aligned
    float4* ls = (float4*)s;

    // ---- phase A: stage target chunk (960 float4; 7 full rounds + half) ----
    {
        const float4* gt = (const float4*)(target + blockBase);
#pragma unroll
        for (int r = 0; r < 7; ++r) {
            int i = r * BLOCK + tid;
            ls[i] = gt[i];
        }
        if (tid < 64) ls[896 + tid] = gt[896 + tid];   // wave-uniform branch
    }
    __syncthreads();

    // ---- copy this thread's 30 target floats to registers (static idx only) ----
    float tl[30];
    {
        const float2* lp2 = (const float2*)(s + tid * 30);     // 120 B offset, 8B aligned
#pragma unroll
        for (int k = 0; k < 15; ++k) {
            float2 v = lp2[k];
            tl[2 * k] = v.x; tl[2 * k + 1] = v.y;
        }
    }
    __syncthreads();                           // all reads done before overwrite

    // ---- phase B: stage pred chunk into the same buffer ----
    {
        const float4* gp = (const float4*)(pred + blockBase);
#pragma unroll
        for (int r = 0; r < 7; ++r) {
            int i = r * BLOCK + tid;
            ls[i] = gp[i];
        }
        if (tid < 64) ls[896 + tid] = gp[896 + tid];
    }
    __syncthreads();

    // ---- compute: pred from LDS, target from regs (math identical to R2) ----
    int c = blockIdx.x * CPB + tid;
    unsigned cell = (unsigned)c % 49u;
    float fi = (float)(cell / 7u);
    float fj = (float)(cell % 7u);

    const float* pl = s + tid * 30;            // stride-30: mild bank alias, negligible

    bool obj = tl[4] > 0.0f;                   // target[...,4] is exactly 1.0 or 0.0

    float iou1 = iou_fn(tl, pl, fi, fj);
    float iou2 = iou_fn(tl, pl + 5, fi, fj);
    bool choose1 = iou1 > iou2;
    float m1 = (obj && choose1 && (iou1 != 0.0f)) ? 1.0f : 0.0f;
    float m2 = (obj && !choose1 && (iou2 != 0.0f)) ? 1.0f : 0.0f;

    float obj_loss = m1 * sq(iou1 - pl[4]) + m2 * sq(iou2 - pl[9]);

    float xy = m1 * (sq(tl[0] - pl[0]) + sq(tl[1] - pl[1]))
             + m2 * (sq(tl[5] - pl[5]) + sq(tl[6] - pl[6]));

    float wh = m1 * (sq(sqrtf(tl[2]) - sqrtf(pl[2])) + sq(sqrtf(tl[3]) - sqrtf(pl[3])))
             + m2 * (sq(sqrtf(tl[7]) - sqrtf(pl[7])) + sq(sqrtf(tl[8]) - sqrtf(pl[8])));

    float noobj = 0.0f;
#pragma unroll
    for (int k = 0; k < 6; ++k) {
        int ci = 4 + 5 * k;                    // 4, 9, 14, 19, 24, 29
        noobj += sq(tl[ci] - pl[ci]);
    }
    if (obj) noobj = 0.0f;

    float clsum = 0.0f;
#pragma unroll
    for (int k = 10; k < 30; ++k) clsum += sq(pl[k] - tl[k]);
    if (!obj) clsum = 0.0f;

    float conf = obj_loss + 0.5f * noobj;
    float reg  = xy + wh;
    float cls  = clsum;

#pragma unroll
    for (int off = 32; off > 0; off >>= 1) {
        conf += __shfl_down(conf, off, 64);
        reg  += __shfl_down(reg,  off, 64);
        cls  += __shfl_down(cls,  off, 64);
    }

    __shared__ float sr[3][2];
    int lane = tid & 63;
    int wave = tid >> 6;
    if (lane == 0) { sr[0][wave] = conf; sr[1][wave] = reg; sr[2][wave] = cls; }
    __syncthreads();
    if (tid == 0) {
        const float invB = 1.0f / 8192.0f;     // sum-then-scale, matches ref order
        partials[blockIdx.x] = make_float4(
            (sr[0][0] + sr[0][1]) * invB,
            (sr[1][0] + sr[1][1]) * (5.0f * invB),
            (sr[2][0] + sr[2][1]) * invB,
            0.0f);
    }
}

// Pass 2: fold 3136 slots -> 3 outputs (plain stores overwrite poisoned d_out).
// Kernel boundary on the stream guarantees visibility of pass-1 stores.
__global__ __launch_bounds__(256) void yolo_final_kernel(
        const float4* __restrict__ partials, float* __restrict__ out) {
    int tid = threadIdx.x;
    float a = 0.0f, b = 0.0f, d = 0.0f;
    for (int i = tid; i < NBLOCKS; i += 256) {
        float4 v = partials[i];
        a += v.x; b += v.y; d += v.z;
    }
#pragma unroll
    for (int off = 32; off > 0; off >>= 1) {
        a += __shfl_down(a, off, 64);
        b += __shfl_down(b, off, 64);
        d += __shfl_down(d, off, 64);
    }
    __shared__ float s[3][4];
    int lane = tid & 63;
    int wave = tid >> 6;
    if (lane == 0) { s[0][wave] = a; s[1][wave] = b; s[2][wave] = d; }
    __syncthreads();
    if (tid == 0) {
        out[0] = s[0][0] + s[0][1] + s[0][2] + s[0][3];
        out[1] = s[1][0] + s[1][1] + s[1][2] + s[1][3];
        out[2] = s[2][0] + s[2][1] + s[2][2] + s[2][3];
    }
}

extern "C" void kernel_launch(void* const* d_in, const int* in_sizes, int n_in,
                              void* d_out, int out_size, void* d_ws, size_t ws_size,
                              hipStream_t stream) {
    const float* pred   = (const float*)d_in[0];
    const float* target = (const float*)d_in[1];
    float* out = (float*)d_out;
    float4* partials = (float4*)d_ws;          // 3136 * 16 B; every slot written before read
    yolo_part_kernel<<<NBLOCKS, BLOCK, 0, stream>>>(pred, target, partials);
    yolo_final_kernel<<<1, 256, 0, stream>>>(partials, out);
}

// Round 5
// 109.884 us; speedup vs baseline: 2.0388x; 1.0197x over previous
//
#include <hip/hip_runtime.h>

#define NCELLS (8192 * 7 * 7)      // 401408 cells of 30 floats each
#define BLOCK 128                  // 2 waves
#define CPB 128                    // cells per block
#define NBLOCKS (NCELLS / CPB)     // 3136 exactly
// Two-phase LDS (15360 B reused: target then pred) -> 10 blocks/CU = 20 waves/CU.
// Staging via global_load_lds width=16: linear dest (base + lane*16) is exactly
// the supported pattern; no VGPR round-trip, no ds_writes.

__device__ __forceinline__ float sq(float x) { return x * x; }

__device__ __forceinline__ float iou_fn(const float* t, const float* p, float fi, float fj) {
    const float STEP = 1.0f / 7.0f;
    float w1 = t[2], h1 = t[3];
    float x1 = (t[0] + fj) * STEP, y1 = (t[1] + fi) * STEP;
    float a1 = fmaxf(x1 - w1 * 0.5f, 0.0f);
    float b1 = fmaxf(y1 - h1 * 0.5f, 0.0f);
    float w2 = p[2], h2 = p[3];
    float x2 = (p[0] + fj) * STEP, y2 = (p[1] + fi) * STEP;
    float a2 = fmaxf(x2 - w2 * 0.5f, 0.0f);
    float b2 = fmaxf(y2 - h2 * 0.5f, 0.0f);
    float iw = w1 + w2 - (fmaxf(a1 + w1, a2 + w2) - fminf(a1, a2));
    float ih = h1 + h2 - (fmaxf(b1 + h1, b2 + h2) - fminf(b1, b2));
    bool valid = (iw > 0.0f) && (ih > 0.0f);
    float inter = valid ? iw * ih : 0.0f;
    float uni = w1 * h1 + w2 * h2 - inter;
    return valid ? inter / uni : 0.0f;
}

// NO fences/atomics (R3: per-block __threadfence = serialized cross-XCD L2
// writebacks, 7x regression). Kernel-boundary visibility is the cheap path.
__global__ __launch_bounds__(BLOCK, 5) void yolo_part_kernel(
        const float* __restrict__ pred, const float* __restrict__ target,
        float4* __restrict__ partials) {
    __shared__ float s[CPB * 30];              // 15360 B, reused: target then pred
    const int tid = threadIdx.x;
    const size_t blockBase = (size_t)blockIdx.x * (CPB * 30);   // floats, 16B-aligned
    float4* ls = (float4*)s;

    // ---- phase A: stage target chunk (960 float4; 7 full rounds + half) ----
    {
        const float4* gt = (const float4*)(target + blockBase);
#pragma unroll
        for (int r = 0; r < 7; ++r) {
            int i = r * BLOCK + tid;
            __builtin_amdgcn_global_load_lds(
                (const __attribute__((address_space(1))) void*)&gt[i],
                (__attribute__((address_space(3))) void*)&ls[i], 16, 0, 0);
        }
        if (tid < 64) {                        // wave-uniform branch; lane-linear dest
            int i = 896 + tid;
            __builtin_amdgcn_global_load_lds(
                (const __attribute__((address_space(1))) void*)&gt[i],
                (__attribute__((address_space(3))) void*)&ls[i], 16, 0, 0);
        }
    }
    __syncthreads();                           // compiler drains vmcnt(0) before barrier

    // ---- copy this thread's 30 target floats to registers (static idx only) ----
    float tl[30];
    {
        const float2* lp2 = (const float2*)(s + tid * 30);     // 120 B offset, 8B aligned
#pragma unroll
        for (int k = 0; k < 15; ++k) {
            float2 v = lp2[k];
            tl[2 * k] = v.x; tl[2 * k + 1] = v.y;
        }
    }
    __syncthreads();                           // all reads done before overwrite

    // ---- phase B: stage pred chunk into the same buffer ----
    {
        const float4* gp = (const float4*)(pred + blockBase);
#pragma unroll
        for (int r = 0; r < 7; ++r) {
            int i = r * BLOCK + tid;
            __builtin_amdgcn_global_load_lds(
                (const __attribute__((address_space(1))) void*)&gp[i],
                (__attribute__((address_space(3))) void*)&ls[i], 16, 0, 0);
        }
        if (tid < 64) {
            int i = 896 + tid;
            __builtin_amdgcn_global_load_lds(
                (const __attribute__((address_space(1))) void*)&gp[i],
                (__attribute__((address_space(3))) void*)&ls[i], 16, 0, 0);
        }
    }
    __syncthreads();

    // ---- compute: pred from LDS, target from regs (math identical to R2/R4) ----
    int c = blockIdx.x * CPB + tid;
    unsigned cell = (unsigned)c % 49u;
    float fi = (float)(cell / 7u);
    float fj = (float)(cell % 7u);

    const float* pl = s + tid * 30;            // stride-30: mild bank alias, negligible

    bool obj = tl[4] > 0.0f;                   // target[...,4] is exactly 1.0 or 0.0

    float iou1 = iou_fn(tl, pl, fi, fj);
    float iou2 = iou_fn(tl, pl + 5, fi, fj);
    bool choose1 = iou1 > iou2;
    float m1 = (obj && choose1 && (iou1 != 0.0f)) ? 1.0f : 0.0f;
    float m2 = (obj && !choose1 && (iou2 != 0.0f)) ? 1.0f : 0.0f;

    float obj_loss = m1 * sq(iou1 - pl[4]) + m2 * sq(iou2 - pl[9]);

    float xy = m1 * (sq(tl[0] - pl[0]) + sq(tl[1] - pl[1]))
             + m2 * (sq(tl[5] - pl[5]) + sq(tl[6] - pl[6]));

    float wh = m1 * (sq(sqrtf(tl[2]) - sqrtf(pl[2])) + sq(sqrtf(tl[3]) - sqrtf(pl[3])))
             + m2 * (sq(sqrtf(tl[7]) - sqrtf(pl[7])) + sq(sqrtf(tl[8]) - sqrtf(pl[8])));

    float noobj = 0.0f;
#pragma unroll
    for (int k = 0; k < 6; ++k) {
        int ci = 4 + 5 * k;                    // 4, 9, 14, 19, 24, 29
        noobj += sq(tl[ci] - pl[ci]);
    }
    if (obj) noobj = 0.0f;

    float clsum = 0.0f;
#pragma unroll
    for (int k = 10; k < 30; ++k) clsum += sq(pl[k] - tl[k]);
    if (!obj) clsum = 0.0f;

    float conf = obj_loss + 0.5f * noobj;
    float reg  = xy + wh;
    float cls  = clsum;

#pragma unroll
    for (int off = 32; off > 0; off >>= 1) {
        conf += __shfl_down(conf, off, 64);
        reg  += __shfl_down(reg,  off, 64);
        cls  += __shfl_down(cls,  off, 64);
    }

    __shared__ float sr[3][2];
    int lane = tid & 63;
    int wave = tid >> 6;
    if (lane == 0) { sr[0][wave] = conf; sr[1][wave] = reg; sr[2][wave] = cls; }
    __syncthreads();
    if (tid == 0) {
        const float invB = 1.0f / 8192.0f;     // sum-then-scale, matches ref order
        partials[blockIdx.x] = make_float4(
            (sr[0][0] + sr[0][1]) * invB,
            (sr[1][0] + sr[1][1]) * (5.0f * invB),
            (sr[2][0] + sr[2][1]) * invB,
            0.0f);
    }
}

// Pass 2: fold 3136 slots -> 3 outputs. 1024 threads (16 waves) so the
// remote-L2/L3 partial reads overlap (3 rounds instead of 13 latency chains).
__global__ __launch_bounds__(1024) void yolo_final_kernel(
        const float4* __restrict__ partials, float* __restrict__ out) {
    int tid = threadIdx.x;
    float a = 0.0f, b = 0.0f, d = 0.0f;
    for (int i = tid; i < NBLOCKS; i += 1024) {
        float4 v = partials[i];
        a += v.x; b += v.y; d += v.z;
    }
#pragma unroll
    for (int off = 32; off > 0; off >>= 1) {
        a += __shfl_down(a, off, 64);
        b += __shfl_down(b, off, 64);
        d += __shfl_down(d, off, 64);
    }
    __shared__ float s[3][16];
    int lane = tid & 63;
    int wave = tid >> 6;
    if (lane == 0) { s[0][wave] = a; s[1][wave] = b; s[2][wave] = d; }
    __syncthreads();
    if (tid == 0) {
        float oa = 0.0f, ob = 0.0f, od = 0.0f;
#pragma unroll
        for (int w = 0; w < 16; ++w) { oa += s[0][w]; ob += s[1][w]; od += s[2][w]; }
        out[0] = oa; out[1] = ob; out[2] = od;
    }
}

extern "C" void kernel_launch(void* const* d_in, const int* in_sizes, int n_in,
                              void* d_out, int out_size, void* d_ws, size_t ws_size,
                              hipStream_t stream) {
    const float* pred   = (const float*)d_in[0];
    const float* target = (const float*)d_in[1];
    float* out = (float*)d_out;
    float4* partials = (float4*)d_ws;          // 3136 * 16 B; every slot written before read
    yolo_part_kernel<<<NBLOCKS, BLOCK, 0, stream>>>(pred, target, partials);
    yolo_final_kernel<<<1, 1024, 0, stream>>>(partials, out);
}